// Round 9
// baseline (218.939 us; speedup 1.0000x reference)
//
#include <hip/hip_runtime.h>

// Elementwise clamp: out = min(max(x, lo), hi)
// x: 33,554,432 fp32 (4194304 x 8). 128 MiB read + 128 MiB write.
//
// R9 = R8 resubmitted verbatim (R8 was an infra failure: "container failed
// twice" — kernel never ran; keep the A/B vs R7 clean).
//
// BURST structure (4 back-to-back loads per thread, no store before any
// load) + the NONTEMPORAL flavor that won on both tested structures
// (R1 vs R2: -11 us; R7 vs R0: -4 us). Theory: cached-burst (R4, 78.5 us)
// lost to cached one-shot (R0, ~71 us) because 64 MiB of in-flight load
// ALLOCATIONS thrashed L2/L3 against fill-resident lines; nt loads remove
// allocation while keeping 4x the per-thread read MLP that one-shot lacks
// (one-shot waves each pay a full cold HBM round-trip).
// Flavor identical to R7 (nt both); single variable vs R7 = structure.
// 8192 blocks x 256 threads x 4 float4 = 8,388,608 float4s exact.
//
// Pre-commit: if total >= 218 us (no better than R7), the grid is
// exhausted -> declare roofline next round and revert to R7.

typedef float f32x4 __attribute__((ext_vector_type(4)));

#define PT 4          // float4s per thread
#define BLOCK 256

__device__ __forceinline__ f32x4 clamp4(f32x4 v, float lo, float hi) {
    // fminf(fmaxf(..)) -> v_med3_f32 clamp idiom
    v.x = fminf(fmaxf(v.x, lo), hi);
    v.y = fminf(fmaxf(v.y, lo), hi);
    v.z = fminf(fmaxf(v.z, lo), hi);
    v.w = fminf(fmaxf(v.w, lo), hi);
    return v;
}

__global__ void __launch_bounds__(BLOCK) clamp_kernel(
    const f32x4* __restrict__ x,
    const float* __restrict__ cp,
    f32x4* __restrict__ out,
    int n4)
{
    const float lo = cp[0];
    const float hi = cp[1];
    const int base = blockIdx.x * (BLOCK * PT) + threadIdx.x;

    if (base + (PT - 1) * BLOCK < n4) {
        // Fast path: 4 nt loads in flight, zero stores before any load.
        f32x4 v[PT];
#pragma unroll
        for (int k = 0; k < PT; ++k)
            v[k] = __builtin_nontemporal_load(&x[base + k * BLOCK]);
#pragma unroll
        for (int k = 0; k < PT; ++k) {
            f32x4 c = clamp4(v[k], lo, hi);
            __builtin_nontemporal_store(c, &out[base + k * BLOCK]);
        }
    } else {
        // Guarded tail (not taken at the exact 4194304x8 shape).
#pragma unroll
        for (int k = 0; k < PT; ++k) {
            int idx = base + k * BLOCK;
            if (idx < n4) {
                f32x4 v = __builtin_nontemporal_load(&x[idx]);
                __builtin_nontemporal_store(clamp4(v, lo, hi), &out[idx]);
            }
        }
    }
}

extern "C" void kernel_launch(void* const* d_in, const int* in_sizes, int n_in,
                              void* d_out, int out_size, void* d_ws, size_t ws_size,
                              hipStream_t stream)
{
    const f32x4* x = (const f32x4*)d_in[0];
    const float* cp = (const float*)d_in[1];
    f32x4* out = (f32x4*)d_out;

    const int n = in_sizes[0];          // 33,554,432 fp32 elements
    const int n4 = n / 4;               // 8,388,608 float4s (exact)

    const int per_block = BLOCK * PT;   // 1024 float4s per block
    const int grid = (n4 + per_block - 1) / per_block;   // 8192 blocks

    clamp_kernel<<<grid, BLOCK, 0, stream>>>(x, cp, out, n4);
}